// Round 1
// baseline (2161.009 us; speedup 1.0000x reference)
//
#include <hip/hip_runtime.h>
#include <hip/hip_bf16.h>
#include <math.h>

#define NODES 50000
#define EDGES 800000
#define EP    850000      // EDGES + NODES self loops
#define INCH  64
#define HIDD  96
#define NHEAD 4
#define CHD   24
#define NLAY  4
#define NGRF  1024
#define BNEPS 1e-5f

__device__ __forceinline__ float elu1(float v) { return v > 0.f ? v : expm1f(v); }

__device__ __forceinline__ void atomicMaxF(float* addr, float v) {
    if (v >= 0.f) atomicMax((int*)addr, __float_as_int(v));
    else          atomicMin((unsigned int*)addr, __float_as_uint(v));
}

// h0 = elu(x @ W_in + b_in)
__global__ __launch_bounds__(256) void k_in_proj(const float* __restrict__ x,
                                                 const float* __restrict__ W,
                                                 const float* __restrict__ b,
                                                 float* __restrict__ h) {
    int t = blockIdx.x * blockDim.x + threadIdx.x;
    if (t >= NODES * HIDD) return;
    int n = t / HIDD, c = t % HIDD;
    const float* xr = x + n * INCH;
    float acc = b[c];
#pragma unroll
    for (int k = 0; k < INCH; ++k) acc = fmaf(xr[k], W[k * HIDD + c], acc);
    h[t] = elu1(acc);
}

// hp = h @ Wg[i]
__global__ __launch_bounds__(256) void k_proj(const float* __restrict__ h,
                                              const float* __restrict__ W,
                                              float* __restrict__ hp) {
    int t = blockIdx.x * blockDim.x + threadIdx.x;
    if (t >= NODES * HIDD) return;
    int n = t / HIDD, c = t % HIDD;
    const float* hr = h + n * HIDD;
    float acc = 0.f;
#pragma unroll
    for (int k = 0; k < HIDD; ++k) acc = fmaf(hr[k], W[k * HIDD + c], acc);
    hp[t] = acc;
}

// per-(node,head) attention coefficients
__global__ __launch_bounds__(256) void k_att(const float* __restrict__ hp,
                                             const float* __restrict__ asrc,
                                             const float* __restrict__ adst,
                                             float* __restrict__ as_,
                                             float* __restrict__ ad_) {
    int t = blockIdx.x * blockDim.x + threadIdx.x;
    if (t >= NODES * NHEAD) return;
    int n = t / NHEAD, hd = t % NHEAD;
    const float* row = hp + n * HIDD + hd * CHD;
    const float* s = asrc + hd * CHD;
    const float* d = adst + hd * CHD;
    float sa = 0.f, da = 0.f;
#pragma unroll
    for (int c = 0; c < CHD; ++c) { sa = fmaf(row[c], s[c], sa); da = fmaf(row[c], d[c], da); }
    as_[t] = sa; ad_[t] = da;
}

// init m=-inf, z=0, acc=0
__global__ __launch_bounds__(256) void k_init(float* __restrict__ m,
                                              float* __restrict__ z,
                                              float* __restrict__ acc) {
    int t = blockIdx.x * blockDim.x + threadIdx.x;
    if (t >= NODES * HIDD) return;
    acc[t] = 0.f;
    if (t < NODES * NHEAD) { m[t] = -INFINITY; z[t] = 0.f; }
}

__device__ __forceinline__ void edge_sd(int e, const int* __restrict__ S,
                                        const int* __restrict__ D, int& s, int& d) {
    if (e < EDGES) { s = S[e]; d = D[e]; } else { s = e - EDGES; d = s; }
}

// segment max of leaky_relu(as[src]+ad[dst]) over dst
__global__ __launch_bounds__(256) void k_emax(const int* __restrict__ S, const int* __restrict__ D,
                                              const float* __restrict__ as_, const float* __restrict__ ad_,
                                              float* __restrict__ m) {
    int t = blockIdx.x * blockDim.x + threadIdx.x;
    if (t >= EP * NHEAD) return;
    int e = t / NHEAD, hd = t % NHEAD;
    int s, d; edge_sd(e, S, D, s, d);
    float ev = as_[s * NHEAD + hd] + ad_[d * NHEAD + hd];
    ev = ev > 0.f ? ev : 0.2f * ev;
    atomicMaxF(&m[d * NHEAD + hd], ev);
}

// p = exp(e - m[dst]); z[dst] += p
__global__ __launch_bounds__(256) void k_eexp(const int* __restrict__ S, const int* __restrict__ D,
                                              const float* __restrict__ as_, const float* __restrict__ ad_,
                                              const float* __restrict__ m,
                                              float* __restrict__ p, float* __restrict__ z) {
    int t = blockIdx.x * blockDim.x + threadIdx.x;
    if (t >= EP * NHEAD) return;
    int e = t / NHEAD, hd = t % NHEAD;
    int s, d; edge_sd(e, S, D, s, d);
    float ev = as_[s * NHEAD + hd] + ad_[d * NHEAD + hd];
    ev = ev > 0.f ? ev : 0.2f * ev;
    float pv = expf(ev - m[d * NHEAD + hd]);
    p[t] = pv;
    atomicAdd(&z[d * NHEAD + hd], pv);
}

// acc[dst,ch] += hp[src,ch] * alpha(e, head(ch))
__global__ __launch_bounds__(256) void k_eagg(const int* __restrict__ S, const int* __restrict__ D,
                                              const float* __restrict__ p, const float* __restrict__ z,
                                              const float* __restrict__ hp, float* __restrict__ acc) {
    int t = blockIdx.x * blockDim.x + threadIdx.x;
    if (t >= EP * HIDD) return;
    int e = t / HIDD, ch = t % HIDD, hd = ch / CHD;
    int s, d; edge_sd(e, S, D, s, d);
    float alpha = p[e * NHEAD + hd] / (z[d * NHEAD + hd] + 1e-16f);
    atomicAdd(&acc[d * HIDD + ch], hp[s * HIDD + ch] * alpha);
}

// hn = BN(acc + bg); h += elu(hn); pooled[batch[n]] += h
__global__ __launch_bounds__(256) void k_node(const float* __restrict__ acc,
                                              const float* __restrict__ bg,
                                              const float* __restrict__ gamma,
                                              const float* __restrict__ beta,
                                              const float* __restrict__ rm,
                                              const float* __restrict__ rv,
                                              float* __restrict__ h,
                                              const int* __restrict__ batch,
                                              float* __restrict__ pooled) {
    int t = blockIdx.x * blockDim.x + threadIdx.x;
    if (t >= NODES * HIDD) return;
    int n = t / HIDD, c = t % HIDD;
    float hn = acc[t] + bg[c];
    hn = (hn - rm[c]) / sqrtf(rv[c] + BNEPS) * gamma[c] + beta[c];
    float hv = h[t] + elu1(hn);
    h[t] = hv;
    atomicAdd(&pooled[batch[n] * HIDD + c], hv);
}

// per-graph MLP head: z1 = elu(cat(pooled) @ Wjk + bjk); z2 = relu(z1 @ Wh1 + bh1); out = z2 @ Wh2 + bh2
__global__ __launch_bounds__(128) void k_head(const float* __restrict__ pooled,
                                              const float* __restrict__ Wjk, const float* __restrict__ bjk,
                                              const float* __restrict__ Wh1, const float* __restrict__ bh1,
                                              const float* __restrict__ Wh2, const float* __restrict__ bh2,
                                              float* __restrict__ out) {
    __shared__ float pin[NLAY * HIDD];
    __shared__ float z1[HIDD];
    __shared__ float z2[HIDD];
    int g = blockIdx.x, tid = threadIdx.x;
    for (int idx = tid; idx < NLAY * HIDD; idx += blockDim.x) {
        int l = idx / HIDD, c = idx % HIDD;
        pin[idx] = pooled[(size_t)l * NGRF * HIDD + (size_t)g * HIDD + c];
    }
    __syncthreads();
    for (int c = tid; c < HIDD; c += blockDim.x) {
        float a = bjk[c];
        for (int k = 0; k < NLAY * HIDD; ++k) a = fmaf(pin[k], Wjk[k * HIDD + c], a);
        z1[c] = elu1(a);
    }
    __syncthreads();
    for (int c = tid; c < HIDD; c += blockDim.x) {
        float a = bh1[c];
#pragma unroll
        for (int k = 0; k < HIDD; ++k) a = fmaf(z1[k], Wh1[k * HIDD + c], a);
        z2[c] = fmaxf(a, 0.f);
    }
    __syncthreads();
    if (tid < 64) {
        float a = 0.f;
        for (int k = tid; k < HIDD; k += 64) a = fmaf(z2[k], Wh2[k], a);
#pragma unroll
        for (int o = 32; o > 0; o >>= 1) a += __shfl_down(a, o);
        if (tid == 0) out[g] = a + bh2[0];
    }
}

extern "C" void kernel_launch(void* const* d_in, const int* in_sizes, int n_in,
                              void* d_out, int out_size, void* d_ws, size_t ws_size,
                              hipStream_t stream) {
    const float* x     = (const float*)d_in[0];
    const int*   ei    = (const int*)d_in[1];
    const int*   batch = (const int*)d_in[2];
    const float* W_in  = (const float*)d_in[3];
    const float* b_in  = (const float*)d_in[4];
    const float* Wg    = (const float*)d_in[5];
    const float* att_s = (const float*)d_in[6];
    const float* att_d = (const float*)d_in[7];
    const float* bg    = (const float*)d_in[8];
    const float* gamma = (const float*)d_in[9];
    const float* beta  = (const float*)d_in[10];
    const float* rm    = (const float*)d_in[11];
    const float* rv    = (const float*)d_in[12];
    const float* Wjk   = (const float*)d_in[13];
    const float* bjk   = (const float*)d_in[14];
    const float* Wh1   = (const float*)d_in[15];
    const float* bh1   = (const float*)d_in[16];
    const float* Wh2   = (const float*)d_in[17];
    const float* bh2   = (const float*)d_in[18];
    float* out = (float*)d_out;

    const int* S = ei;
    const int* Dd = ei + EDGES;

    // workspace layout (floats)
    float* ws = (float*)d_ws;
    float* h      = ws;                        // N*96
    float* hp     = h    + (size_t)NODES * HIDD;   // N*96
    float* as_    = hp   + (size_t)NODES * HIDD;   // N*4
    float* ad_    = as_  + (size_t)NODES * NHEAD;  // N*4
    float* m      = ad_  + (size_t)NODES * NHEAD;  // N*4
    float* z      = m    + (size_t)NODES * NHEAD;  // N*4
    float* p      = z    + (size_t)NODES * NHEAD;  // EP*4
    float* acc    = p    + (size_t)EP * NHEAD;     // N*96
    float* pooled = acc  + (size_t)NODES * HIDD;   // 4*G*96

    hipMemsetAsync(pooled, 0, sizeof(float) * NLAY * NGRF * HIDD, stream);

    const int TB = 256;
    int gN96 = (NODES * HIDD + TB - 1) / TB;
    int gN4  = (NODES * NHEAD + TB - 1) / TB;
    int gE4  = (EP * NHEAD + TB - 1) / TB;
    int gE96 = (EP * HIDD + TB - 1) / TB;

    k_in_proj<<<gN96, TB, 0, stream>>>(x, W_in, b_in, h);

    for (int i = 0; i < NLAY; ++i) {
        k_proj<<<gN96, TB, 0, stream>>>(h, Wg + (size_t)i * HIDD * HIDD, hp);
        k_att<<<gN4, TB, 0, stream>>>(hp, att_s + i * NHEAD * CHD, att_d + i * NHEAD * CHD, as_, ad_);
        k_init<<<gN96, TB, 0, stream>>>(m, z, acc);
        k_emax<<<gE4, TB, 0, stream>>>(S, Dd, as_, ad_, m);
        k_eexp<<<gE4, TB, 0, stream>>>(S, Dd, as_, ad_, m, p, z);
        k_eagg<<<gE96, TB, 0, stream>>>(S, Dd, p, z, hp, acc);
        k_node<<<gN96, TB, 0, stream>>>(acc, bg + i * HIDD, gamma + i * HIDD, beta + i * HIDD,
                                        rm + i * HIDD, rv + i * HIDD, h, batch,
                                        pooled + (size_t)i * NGRF * HIDD);
    }

    k_head<<<NGRF, 128, 0, stream>>>(pooled, Wjk, bjk, Wh1, bh1, Wh2, bh2, out);
}

// Round 2
// 1156.193 us; speedup vs baseline: 1.8691x; 1.8691x over previous
//
#include <hip/hip_runtime.h>
#include <hip/hip_bf16.h>
#include <math.h>

#define NODES 50000
#define EDGES 800000
#define EP    850000      // EDGES + NODES self loops
#define INCH  64
#define HIDD  96
#define NHEAD 4
#define CHD   24
#define NLAY  4
#define NGRF  1024
#define BNEPS 1e-5f
#define NB    49          // ceil(NODES/1024)

__device__ __forceinline__ float elu1(float v) { return v > 0.f ? v : expm1f(v); }

__device__ __forceinline__ void edge_sd(int e, const int* __restrict__ S,
                                        const int* __restrict__ D, int& s, int& d) {
    if (e < EDGES) { s = S[e]; d = D[e]; } else { s = e - EDGES; d = s; }
}

// ---------------- CSR build (once per call; graph is layer-invariant) ----------------

__global__ __launch_bounds__(256) void k_count(const int* __restrict__ S, const int* __restrict__ D,
                                               int* __restrict__ cnt) {
    int e = blockIdx.x * blockDim.x + threadIdx.x;
    if (e >= EP) return;
    int s, d; edge_sd(e, S, D, s, d);
    atomicAdd(&cnt[d], 1);
}

__global__ __launch_bounds__(1024) void k_scan1(const int* __restrict__ cnt,
                                                int* __restrict__ off, int* __restrict__ bsum) {
    __shared__ int sd[1024];
    int t = threadIdx.x;
    int i = blockIdx.x * 1024 + t;
    int v = (i < NODES) ? cnt[i] : 0;
    sd[t] = v; __syncthreads();
    for (int o = 1; o < 1024; o <<= 1) {
        int tv = (t >= o) ? sd[t - o] : 0;
        __syncthreads();
        sd[t] += tv; __syncthreads();
    }
    if (i < NODES) off[i] = sd[t] - v;           // exclusive within block
    if (t == 1023) bsum[blockIdx.x] = sd[1023];
}

__global__ void k_scan2(int* __restrict__ bsum, int* __restrict__ off) {
    if (threadIdx.x == 0 && blockIdx.x == 0) {
        int run = 0;
        for (int b = 0; b < NB; ++b) { int tv = bsum[b]; bsum[b] = run; run += tv; }
        off[NODES] = run;                        // == EP
    }
}

__global__ __launch_bounds__(1024) void k_scan3(int* __restrict__ off, const int* __restrict__ bsum,
                                                int* __restrict__ cursor) {
    int i = blockIdx.x * 1024 + threadIdx.x;
    if (i >= NODES) return;
    int o = off[i] + bsum[blockIdx.x];
    off[i] = o;
    cursor[i] = o;
}

__global__ __launch_bounds__(256) void k_scatter(const int* __restrict__ S, const int* __restrict__ D,
                                                 int* __restrict__ cursor, int* __restrict__ csr_src) {
    int e = blockIdx.x * blockDim.x + threadIdx.x;
    if (e >= EP) return;
    int s, d; edge_sd(e, S, D, s, d);
    int pos = atomicAdd(&cursor[d], 1);
    csr_src[pos] = s;
}

// ---------------- dense node kernels ----------------

__global__ __launch_bounds__(256) void k_in_proj(const float* __restrict__ x,
                                                 const float* __restrict__ W,
                                                 const float* __restrict__ b,
                                                 float* __restrict__ h) {
    int t = blockIdx.x * blockDim.x + threadIdx.x;
    if (t >= NODES * HIDD) return;
    int n = t / HIDD, c = t % HIDD;
    const float* xr = x + n * INCH;
    float acc = b[c];
#pragma unroll
    for (int k = 0; k < INCH; ++k) acc = fmaf(xr[k], W[k * HIDD + c], acc);
    h[t] = elu1(acc);
}

__global__ __launch_bounds__(256) void k_proj(const float* __restrict__ h,
                                              const float* __restrict__ W,
                                              float* __restrict__ hp) {
    int t = blockIdx.x * blockDim.x + threadIdx.x;
    if (t >= NODES * HIDD) return;
    int n = t / HIDD, c = t % HIDD;
    const float* hr = h + n * HIDD;
    float acc = 0.f;
#pragma unroll
    for (int k = 0; k < HIDD; ++k) acc = fmaf(hr[k], W[k * HIDD + c], acc);
    hp[t] = acc;
}

__global__ __launch_bounds__(256) void k_att(const float* __restrict__ hp,
                                             const float* __restrict__ asrc,
                                             const float* __restrict__ adst,
                                             float* __restrict__ as_,
                                             float* __restrict__ ad_) {
    int t = blockIdx.x * blockDim.x + threadIdx.x;
    if (t >= NODES * NHEAD) return;
    int n = t / NHEAD, hd = t % NHEAD;
    const float* row = hp + n * HIDD + hd * CHD;
    const float* s = asrc + hd * CHD;
    const float* d = adst + hd * CHD;
    float sa = 0.f, da = 0.f;
#pragma unroll
    for (int c = 0; c < CHD; ++c) { sa = fmaf(row[c], s[c], sa); da = fmaf(row[c], d[c], da); }
    as_[t] = sa; ad_[t] = da;
}

// ---------------- edge phase, atomic-free via CSR ----------------

// one wave per dst node: per-head segment softmax, alpha written CSR-ordered
__global__ __launch_bounds__(256) void k_softmax(const int* __restrict__ off,
                                                 const int* __restrict__ csr_src,
                                                 const float* __restrict__ as_,
                                                 const float* __restrict__ ad_,
                                                 float* __restrict__ alpha) {
    int node = blockIdx.x * 4 + (threadIdx.x >> 6);
    if (node >= NODES) return;
    int lane = threadIdx.x & 63;
    int hd = lane & 3;          // head
    int slot0 = lane >> 2;      // 0..15
    int beg = off[node], end = off[node + 1];
    float adv = ad_[node * NHEAD + hd];

    float mx = -INFINITY;
    for (int i = beg + slot0; i < end; i += 16) {
        float ev = as_[csr_src[i] * NHEAD + hd] + adv;
        ev = ev > 0.f ? ev : 0.2f * ev;
        mx = fmaxf(mx, ev);
    }
#pragma unroll
    for (int o = 4; o < 64; o <<= 1) mx = fmaxf(mx, __shfl_xor(mx, o));

    float zz = 0.f;
    for (int i = beg + slot0; i < end; i += 16) {
        float ev = as_[csr_src[i] * NHEAD + hd] + adv;
        ev = ev > 0.f ? ev : 0.2f * ev;
        float pv = expf(ev - mx);
        alpha[i * NHEAD + hd] = pv;
        zz += pv;
    }
#pragma unroll
    for (int o = 4; o < 64; o <<= 1) zz += __shfl_xor(zz, o);

    float inv = 1.f / (zz + 1e-16f);
    for (int i = beg + slot0; i < end; i += 16) alpha[i * NHEAD + hd] *= inv;
}

// one wave per dst node: gather-aggregate (no atomics) + BN + residual ELU + pooled add
__global__ __launch_bounds__(256) void k_aggnode(const int* __restrict__ off,
                                                 const int* __restrict__ csr_src,
                                                 const float* __restrict__ alpha,
                                                 const float* __restrict__ hp,
                                                 const float* __restrict__ bg,
                                                 const float* __restrict__ gamma,
                                                 const float* __restrict__ beta,
                                                 const float* __restrict__ rm,
                                                 const float* __restrict__ rv,
                                                 float* __restrict__ h,
                                                 const int* __restrict__ batch,
                                                 float* __restrict__ pooled) {
    int node = blockIdx.x * 4 + (threadIdx.x >> 6);
    if (node >= NODES) return;
    int lane = threadIdx.x & 63;
    int beg = off[node], end = off[node + 1];

    const int ch0 = lane;            // 0..63
    const int h0 = lane / CHD;       // 0,1,2
    const int ch1 = 64 + lane;       // 64..95 (lane<32 only)
    const int h1 = ch1 / CHD;        // 2 or 3

    float a0 = 0.f, a1 = 0.f;
    for (int i = beg; i < end; ++i) {
        int s = csr_src[i];
        const float* hr = hp + s * HIDD;
        const float* al = alpha + i * NHEAD;
        a0 = fmaf(hr[ch0], al[h0], a0);
        if (lane < 32) a1 = fmaf(hr[ch1], al[h1], a1);
    }

    int gi = batch[node] * HIDD;
    {
        float hn = a0 + bg[ch0];
        hn = (hn - rm[ch0]) / sqrtf(rv[ch0] + BNEPS) * gamma[ch0] + beta[ch0];
        float hv = h[node * HIDD + ch0] + elu1(hn);
        h[node * HIDD + ch0] = hv;
        atomicAdd(&pooled[gi + ch0], hv);
    }
    if (lane < 32) {
        float hn = a1 + bg[ch1];
        hn = (hn - rm[ch1]) / sqrtf(rv[ch1] + BNEPS) * gamma[ch1] + beta[ch1];
        float hv = h[node * HIDD + ch1] + elu1(hn);
        h[node * HIDD + ch1] = hv;
        atomicAdd(&pooled[gi + ch1], hv);
    }
}

// ---------------- per-graph MLP head ----------------

__global__ __launch_bounds__(128) void k_head(const float* __restrict__ pooled,
                                              const float* __restrict__ Wjk, const float* __restrict__ bjk,
                                              const float* __restrict__ Wh1, const float* __restrict__ bh1,
                                              const float* __restrict__ Wh2, const float* __restrict__ bh2,
                                              float* __restrict__ out) {
    __shared__ float pin[NLAY * HIDD];
    __shared__ float z1[HIDD];
    __shared__ float z2[HIDD];
    int g = blockIdx.x, tid = threadIdx.x;
    for (int idx = tid; idx < NLAY * HIDD; idx += blockDim.x) {
        int l = idx / HIDD, c = idx % HIDD;
        pin[idx] = pooled[(size_t)l * NGRF * HIDD + (size_t)g * HIDD + c];
    }
    __syncthreads();
    for (int c = tid; c < HIDD; c += blockDim.x) {
        float a = bjk[c];
        for (int k = 0; k < NLAY * HIDD; ++k) a = fmaf(pin[k], Wjk[k * HIDD + c], a);
        z1[c] = elu1(a);
    }
    __syncthreads();
    for (int c = tid; c < HIDD; c += blockDim.x) {
        float a = bh1[c];
#pragma unroll
        for (int k = 0; k < HIDD; ++k) a = fmaf(z1[k], Wh1[k * HIDD + c], a);
        z2[c] = fmaxf(a, 0.f);
    }
    __syncthreads();
    if (tid < 64) {
        float a = 0.f;
        for (int k = tid; k < HIDD; k += 64) a = fmaf(z2[k], Wh2[k], a);
#pragma unroll
        for (int o = 32; o > 0; o >>= 1) a += __shfl_down(a, o);
        if (tid == 0) out[g] = a + bh2[0];
    }
}

extern "C" void kernel_launch(void* const* d_in, const int* in_sizes, int n_in,
                              void* d_out, int out_size, void* d_ws, size_t ws_size,
                              hipStream_t stream) {
    const float* x     = (const float*)d_in[0];
    const int*   ei    = (const int*)d_in[1];
    const int*   batch = (const int*)d_in[2];
    const float* W_in  = (const float*)d_in[3];
    const float* b_in  = (const float*)d_in[4];
    const float* Wg    = (const float*)d_in[5];
    const float* att_s = (const float*)d_in[6];
    const float* att_d = (const float*)d_in[7];
    const float* bg    = (const float*)d_in[8];
    const float* gamma = (const float*)d_in[9];
    const float* beta  = (const float*)d_in[10];
    const float* rm    = (const float*)d_in[11];
    const float* rv    = (const float*)d_in[12];
    const float* Wjk   = (const float*)d_in[13];
    const float* bjk   = (const float*)d_in[14];
    const float* Wh1   = (const float*)d_in[15];
    const float* bh1   = (const float*)d_in[16];
    const float* Wh2   = (const float*)d_in[17];
    const float* bh2   = (const float*)d_in[18];
    float* out = (float*)d_out;

    const int* S = ei;
    const int* Dd = ei + EDGES;

    // workspace layout
    float* ws = (float*)d_ws;
    float* h      = ws;                               // N*96
    float* hp     = h      + (size_t)NODES * HIDD;    // N*96
    float* as_    = hp     + (size_t)NODES * HIDD;    // N*4
    float* ad_    = as_    + (size_t)NODES * NHEAD;   // N*4
    float* alpha  = ad_    + (size_t)NODES * NHEAD;   // EP*4
    float* pooled = alpha  + (size_t)EP * NHEAD;      // L*G*96
    int*   off    = (int*)(pooled + (size_t)NLAY * NGRF * HIDD);  // N+1
    int*   cursor = off    + NODES + 1;               // N
    int*   csr    = cursor + NODES;                   // EP
    int*   cnt    = csr    + EP;                      // N
    int*   bsum   = cnt    + NODES;                   // NB

    hipMemsetAsync(pooled, 0, sizeof(float) * NLAY * NGRF * HIDD, stream);
    hipMemsetAsync(cnt, 0, sizeof(int) * NODES, stream);

    const int TB = 256;
    int gN96 = (NODES * HIDD + TB - 1) / TB;
    int gN4  = (NODES * NHEAD + TB - 1) / TB;
    int gE   = (EP + TB - 1) / TB;
    int gWave = NODES / 4;   // 12500 (exact)

    // CSR build (graph is identical across layers)
    k_count<<<gE, TB, 0, stream>>>(S, Dd, cnt);
    k_scan1<<<NB, 1024, 0, stream>>>(cnt, off, bsum);
    k_scan2<<<1, 64, 0, stream>>>(bsum, off);
    k_scan3<<<NB, 1024, 0, stream>>>(off, bsum, cursor);
    k_scatter<<<gE, TB, 0, stream>>>(S, Dd, cursor, csr);

    k_in_proj<<<gN96, TB, 0, stream>>>(x, W_in, b_in, h);

    for (int i = 0; i < NLAY; ++i) {
        k_proj<<<gN96, TB, 0, stream>>>(h, Wg + (size_t)i * HIDD * HIDD, hp);
        k_att<<<gN4, TB, 0, stream>>>(hp, att_s + i * NHEAD * CHD, att_d + i * NHEAD * CHD, as_, ad_);
        k_softmax<<<gWave, TB, 0, stream>>>(off, csr, as_, ad_, alpha);
        k_aggnode<<<gWave, TB, 0, stream>>>(off, csr, alpha, hp,
                                            bg + i * HIDD, gamma + i * HIDD, beta + i * HIDD,
                                            rm + i * HIDD, rv + i * HIDD, h, batch,
                                            pooled + (size_t)i * NGRF * HIDD);
    }

    k_head<<<NGRF, 128, 0, stream>>>(pooled, Wjk, bjk, Wh1, bh1, Wh2, bh2, out);
}

// Round 3
// 910.666 us; speedup vs baseline: 2.3730x; 1.2696x over previous
//
#include <hip/hip_runtime.h>
#include <hip/hip_bf16.h>
#include <math.h>

#define NODES 50000
#define EDGES 800000
#define EP    850000      // EDGES + NODES self loops
#define INCH  64
#define HIDD  96
#define NHEAD 4
#define CHD   24
#define NLAY  4
#define NGRF  1024
#define BNEPS 1e-5f
#define NB    49          // ceil(NODES/1024)

__device__ __forceinline__ float elu1(float v) { return v > 0.f ? v : expm1f(v); }

__device__ __forceinline__ void edge_sd(int e, const int* __restrict__ S,
                                        const int* __restrict__ D, int& s, int& d) {
    if (e < EDGES) { s = S[e]; d = D[e]; } else { s = e - EDGES; d = s; }
}

// ---------------- CSR build (once per call; graph is layer-invariant) ----------------

__global__ __launch_bounds__(256) void k_count(const int* __restrict__ S, const int* __restrict__ D,
                                               int* __restrict__ cnt) {
    int e = blockIdx.x * blockDim.x + threadIdx.x;
    if (e >= EP) return;
    int s, d; edge_sd(e, S, D, s, d);
    atomicAdd(&cnt[d], 1);
}

__global__ __launch_bounds__(1024) void k_scan1(const int* __restrict__ cnt,
                                                int* __restrict__ off, int* __restrict__ bsum) {
    __shared__ int sd[1024];
    int t = threadIdx.x;
    int i = blockIdx.x * 1024 + t;
    int v = (i < NODES) ? cnt[i] : 0;
    sd[t] = v; __syncthreads();
    for (int o = 1; o < 1024; o <<= 1) {
        int tv = (t >= o) ? sd[t - o] : 0;
        __syncthreads();
        sd[t] += tv; __syncthreads();
    }
    if (i < NODES) off[i] = sd[t] - v;           // exclusive within block
    if (t == 1023) bsum[blockIdx.x] = sd[1023];
}

__global__ void k_scan2(int* __restrict__ bsum, int* __restrict__ off) {
    if (threadIdx.x == 0 && blockIdx.x == 0) {
        int run = 0;
        for (int b = 0; b < NB; ++b) { int tv = bsum[b]; bsum[b] = run; run += tv; }
        off[NODES] = run;                        // == EP
    }
}

__global__ __launch_bounds__(1024) void k_scan3(int* __restrict__ off, const int* __restrict__ bsum,
                                                int* __restrict__ cursor) {
    int i = blockIdx.x * 1024 + threadIdx.x;
    if (i >= NODES) return;
    int o = off[i] + bsum[blockIdx.x];
    off[i] = o;
    cursor[i] = o;
}

__global__ __launch_bounds__(256) void k_scatter(const int* __restrict__ S, const int* __restrict__ D,
                                                 int* __restrict__ cursor, int* __restrict__ csr_src) {
    int e = blockIdx.x * blockDim.x + threadIdx.x;
    if (e >= EP) return;
    int s, d; edge_sd(e, S, D, s, d);
    int pos = atomicAdd(&cursor[d], 1);
    csr_src[pos] = s;
}

// ---------------- dense node kernels (register-tiled, scalar-W GEMM) ----------------

// h0 = elu(x @ W_in + b_in). lane=node, wave-uniform 24-channel group -> W via s_loads.
__global__ __launch_bounds__(256) void k_in_proj(const float* __restrict__ x,
                                                 const float* __restrict__ W,
                                                 const float* __restrict__ b,
                                                 float* __restrict__ h) {
    int node = blockIdx.x * 64 + (threadIdx.x & 63);
    if (node >= NODES) return;
    int cbase = __builtin_amdgcn_readfirstlane((threadIdx.x >> 6) * CHD);
    const float* __restrict__ Wc = W + cbase;
    const float* __restrict__ xr = x + (size_t)node * INCH;

    float acc[CHD];
#pragma unroll
    for (int j = 0; j < CHD; ++j) acc[j] = Wc[-cbase + 0] * 0.f; // init below properly
#pragma unroll
    for (int j = 0; j < CHD; ++j) acc[j] = b[cbase + j];

#pragma unroll
    for (int k0 = 0; k0 < INCH; k0 += 4) {
        float4 hv = *(const float4*)(xr + k0);
        const float hvv[4] = {hv.x, hv.y, hv.z, hv.w};
#pragma unroll
        for (int kk = 0; kk < 4; ++kk) {
#pragma unroll
            for (int j = 0; j < CHD; ++j)
                acc[j] = fmaf(hvv[kk], Wc[(k0 + kk) * HIDD + j], acc[j]);
        }
    }
    float* hrow = h + (size_t)node * HIDD + cbase;
#pragma unroll
    for (int j = 0; j < CHD; ++j) hrow[j] = elu1(acc[j]);
}

// hp = h @ Wg[i]; fused per-head attention dots (cgroup == head).
__global__ __launch_bounds__(256) void k_proj(const float* __restrict__ h,
                                              const float* __restrict__ W,
                                              const float* __restrict__ asrc,
                                              const float* __restrict__ adst,
                                              float* __restrict__ hp,
                                              float* __restrict__ as_,
                                              float* __restrict__ ad_) {
    int node = blockIdx.x * 64 + (threadIdx.x & 63);
    if (node >= NODES) return;
    int head = __builtin_amdgcn_readfirstlane(threadIdx.x >> 6);   // 0..3
    int cbase = head * CHD;
    const float* __restrict__ Wc = W + cbase;
    const float* __restrict__ hr = h + (size_t)node * HIDD;

    float acc[CHD] = {};
#pragma unroll
    for (int k0 = 0; k0 < HIDD; k0 += 4) {
        float4 hv = *(const float4*)(hr + k0);
        const float hvv[4] = {hv.x, hv.y, hv.z, hv.w};
#pragma unroll
        for (int kk = 0; kk < 4; ++kk) {
#pragma unroll
            for (int j = 0; j < CHD; ++j)
                acc[j] = fmaf(hvv[kk], Wc[(k0 + kk) * HIDD + j], acc[j]);
        }
    }
    float* orow = hp + (size_t)node * HIDD + cbase;
#pragma unroll
    for (int j = 0; j < CHD; ++j) orow[j] = acc[j];

    const float* __restrict__ s = asrc + head * CHD;
    const float* __restrict__ d = adst + head * CHD;
    float sa = 0.f, da = 0.f;
#pragma unroll
    for (int j = 0; j < CHD; ++j) { sa = fmaf(acc[j], s[j], sa); da = fmaf(acc[j], d[j], da); }
    as_[node * NHEAD + head] = sa;
    ad_[node * NHEAD + head] = da;
}

// ---------------- edge phase, atomic-free via CSR ----------------

// one wave per dst node: per-head segment softmax, alpha written CSR-ordered
__global__ __launch_bounds__(256) void k_softmax(const int* __restrict__ off,
                                                 const int* __restrict__ csr_src,
                                                 const float* __restrict__ as_,
                                                 const float* __restrict__ ad_,
                                                 float* __restrict__ alpha) {
    int node = blockIdx.x * 4 + (threadIdx.x >> 6);
    if (node >= NODES) return;
    int lane = threadIdx.x & 63;
    int hd = lane & 3;          // head
    int slot0 = lane >> 2;      // 0..15
    int beg = off[node], end = off[node + 1];
    float adv = ad_[node * NHEAD + hd];

    float mx = -INFINITY;
    for (int i = beg + slot0; i < end; i += 16) {
        float ev = as_[csr_src[i] * NHEAD + hd] + adv;
        ev = ev > 0.f ? ev : 0.2f * ev;
        mx = fmaxf(mx, ev);
    }
#pragma unroll
    for (int o = 4; o < 64; o <<= 1) mx = fmaxf(mx, __shfl_xor(mx, o));

    float zz = 0.f;
    for (int i = beg + slot0; i < end; i += 16) {
        float ev = as_[csr_src[i] * NHEAD + hd] + adv;
        ev = ev > 0.f ? ev : 0.2f * ev;
        float pv = expf(ev - mx);
        alpha[i * NHEAD + hd] = pv;
        zz += pv;
    }
#pragma unroll
    for (int o = 4; o < 64; o <<= 1) zz += __shfl_xor(zz, o);

    float inv = 1.f / (zz + 1e-16f);
    for (int i = beg + slot0; i < end; i += 16) alpha[i * NHEAD + hd] *= inv;
}

// one wave per dst node: gather-aggregate (no atomics) + BN + residual ELU + pooled add
__global__ __launch_bounds__(256) void k_aggnode(const int* __restrict__ off,
                                                 const int* __restrict__ csr_src,
                                                 const float* __restrict__ alpha,
                                                 const float* __restrict__ hp,
                                                 const float* __restrict__ bg,
                                                 const float* __restrict__ gamma,
                                                 const float* __restrict__ beta,
                                                 const float* __restrict__ rm,
                                                 const float* __restrict__ rv,
                                                 float* __restrict__ h,
                                                 const int* __restrict__ batch,
                                                 float* __restrict__ pooled) {
    int node = blockIdx.x * 4 + (threadIdx.x >> 6);
    if (node >= NODES) return;
    int lane = threadIdx.x & 63;
    int beg = off[node], end = off[node + 1];

    const int ch0 = lane;            // 0..63
    const int h0 = lane / CHD;       // 0,1,2
    const int ch1 = 64 + lane;       // 64..95 (lane<32 only)
    const int h1 = ch1 / CHD;        // 2 or 3

    float a0 = 0.f, a1 = 0.f;
    for (int i = beg; i < end; ++i) {
        int s = csr_src[i];
        const float* hr = hp + (size_t)s * HIDD;
        const float* al = alpha + (size_t)i * NHEAD;
        a0 = fmaf(hr[ch0], al[h0], a0);
        if (lane < 32) a1 = fmaf(hr[ch1], al[h1], a1);
    }

    int gi = batch[node] * HIDD;
    {
        float hn = a0 + bg[ch0];
        hn = (hn - rm[ch0]) / sqrtf(rv[ch0] + BNEPS) * gamma[ch0] + beta[ch0];
        float hv = h[(size_t)node * HIDD + ch0] + elu1(hn);
        h[(size_t)node * HIDD + ch0] = hv;
        atomicAdd(&pooled[gi + ch0], hv);
    }
    if (lane < 32) {
        float hn = a1 + bg[ch1];
        hn = (hn - rm[ch1]) / sqrtf(rv[ch1] + BNEPS) * gamma[ch1] + beta[ch1];
        float hv = h[(size_t)node * HIDD + ch1] + elu1(hn);
        h[(size_t)node * HIDD + ch1] = hv;
        atomicAdd(&pooled[gi + ch1], hv);
    }
}

// ---------------- per-graph MLP head ----------------

__global__ __launch_bounds__(128) void k_head(const float* __restrict__ pooled,
                                              const float* __restrict__ Wjk, const float* __restrict__ bjk,
                                              const float* __restrict__ Wh1, const float* __restrict__ bh1,
                                              const float* __restrict__ Wh2, const float* __restrict__ bh2,
                                              float* __restrict__ out) {
    __shared__ float pin[NLAY * HIDD];
    __shared__ float z1[HIDD];
    __shared__ float z2[HIDD];
    int g = blockIdx.x, tid = threadIdx.x;
    for (int idx = tid; idx < NLAY * HIDD; idx += blockDim.x) {
        int l = idx / HIDD, c = idx % HIDD;
        pin[idx] = pooled[(size_t)l * NGRF * HIDD + (size_t)g * HIDD + c];
    }
    __syncthreads();
    for (int c = tid; c < HIDD; c += blockDim.x) {
        float a = bjk[c];
        for (int k = 0; k < NLAY * HIDD; ++k) a = fmaf(pin[k], Wjk[k * HIDD + c], a);
        z1[c] = elu1(a);
    }
    __syncthreads();
    for (int c = tid; c < HIDD; c += blockDim.x) {
        float a = bh1[c];
#pragma unroll
        for (int k = 0; k < HIDD; ++k) a = fmaf(z1[k], Wh1[k * HIDD + c], a);
        z2[c] = fmaxf(a, 0.f);
    }
    __syncthreads();
    if (tid < 64) {
        float a = 0.f;
        for (int k = tid; k < HIDD; k += 64) a = fmaf(z2[k], Wh2[k], a);
#pragma unroll
        for (int o = 32; o > 0; o >>= 1) a += __shfl_down(a, o);
        if (tid == 0) out[g] = a + bh2[0];
    }
}

extern "C" void kernel_launch(void* const* d_in, const int* in_sizes, int n_in,
                              void* d_out, int out_size, void* d_ws, size_t ws_size,
                              hipStream_t stream) {
    const float* x     = (const float*)d_in[0];
    const int*   ei    = (const int*)d_in[1];
    const int*   batch = (const int*)d_in[2];
    const float* W_in  = (const float*)d_in[3];
    const float* b_in  = (const float*)d_in[4];
    const float* Wg    = (const float*)d_in[5];
    const float* att_s = (const float*)d_in[6];
    const float* att_d = (const float*)d_in[7];
    const float* bg    = (const float*)d_in[8];
    const float* gamma = (const float*)d_in[9];
    const float* beta  = (const float*)d_in[10];
    const float* rm    = (const float*)d_in[11];
    const float* rv    = (const float*)d_in[12];
    const float* Wjk   = (const float*)d_in[13];
    const float* bjk   = (const float*)d_in[14];
    const float* Wh1   = (const float*)d_in[15];
    const float* bh1   = (const float*)d_in[16];
    const float* Wh2   = (const float*)d_in[17];
    const float* bh2   = (const float*)d_in[18];
    float* out = (float*)d_out;

    const int* S = ei;
    const int* Dd = ei + EDGES;

    // workspace layout
    float* ws = (float*)d_ws;
    float* h      = ws;                               // N*96
    float* hp     = h      + (size_t)NODES * HIDD;    // N*96
    float* as_    = hp     + (size_t)NODES * HIDD;    // N*4
    float* ad_    = as_    + (size_t)NODES * NHEAD;   // N*4
    float* alpha  = ad_    + (size_t)NODES * NHEAD;   // EP*4
    float* pooled = alpha  + (size_t)EP * NHEAD;      // L*G*96
    int*   off    = (int*)(pooled + (size_t)NLAY * NGRF * HIDD);  // N+1
    int*   cursor = off    + NODES + 1;               // N
    int*   csr    = cursor + NODES;                   // EP
    int*   cnt    = csr    + EP;                      // N
    int*   bsum   = cnt    + NODES;                   // NB

    hipMemsetAsync(pooled, 0, sizeof(float) * NLAY * NGRF * HIDD, stream);
    hipMemsetAsync(cnt, 0, sizeof(int) * NODES, stream);

    const int TB = 256;
    int gE   = (EP + TB - 1) / TB;
    int gTile = (NODES + 63) / 64;   // 782 blocks, 64 nodes each
    int gWave = NODES / 4;           // 12500 (exact)

    // CSR build (graph is identical across layers)
    k_count<<<gE, TB, 0, stream>>>(S, Dd, cnt);
    k_scan1<<<NB, 1024, 0, stream>>>(cnt, off, bsum);
    k_scan2<<<1, 64, 0, stream>>>(bsum, off);
    k_scan3<<<NB, 1024, 0, stream>>>(off, bsum, cursor);
    k_scatter<<<gE, TB, 0, stream>>>(S, Dd, cursor, csr);

    k_in_proj<<<gTile, TB, 0, stream>>>(x, W_in, b_in, h);

    for (int i = 0; i < NLAY; ++i) {
        k_proj<<<gTile, TB, 0, stream>>>(h, Wg + (size_t)i * HIDD * HIDD,
                                         att_s + i * NHEAD * CHD, att_d + i * NHEAD * CHD,
                                         hp, as_, ad_);
        k_softmax<<<gWave, TB, 0, stream>>>(off, csr, as_, ad_, alpha);
        k_aggnode<<<gWave, TB, 0, stream>>>(off, csr, alpha, hp,
                                            bg + i * HIDD, gamma + i * HIDD, beta + i * HIDD,
                                            rm + i * HIDD, rv + i * HIDD, h, batch,
                                            pooled + (size_t)i * NGRF * HIDD);
    }

    k_head<<<NGRF, 128, 0, stream>>>(pooled, Wjk, bjk, Wh1, bh1, Wh2, bh2, out);
}

// Round 5
// 721.338 us; speedup vs baseline: 2.9958x; 1.2625x over previous
//
#include <hip/hip_runtime.h>
#include <hip/hip_bf16.h>
#include <math.h>

#define NODES 50000
#define EDGES 800000
#define EP    850000      // EDGES + NODES self loops
#define INCH  64
#define HIDD  96
#define NHEAD 4
#define CHD   24
#define NLAY  4
#define NGRF  1024
#define BNEPS 1e-5f
#define NB    49          // ceil(NODES/1024)
#define NEGBIG (-1.0e30f) // finite -inf sentinel: avoids NaN from exp(-inf - -inf)

__device__ __forceinline__ float elu1(float v) { return v > 0.f ? v : __expf(v) - 1.f; }

__device__ __forceinline__ void edge_sd(int e, const int* __restrict__ S,
                                        const int* __restrict__ D, int& s, int& d) {
    if (e < EDGES) { s = S[e]; d = D[e]; } else { s = e - EDGES; d = s; }
}

// ---------------- CSR build (once per call; graph is layer-invariant) ----------------

__global__ __launch_bounds__(256) void k_count(const int* __restrict__ S, const int* __restrict__ D,
                                               int* __restrict__ cnt) {
    int e = blockIdx.x * blockDim.x + threadIdx.x;
    if (e >= EP) return;
    int s, d; edge_sd(e, S, D, s, d);
    atomicAdd(&cnt[d], 1);
}

__global__ __launch_bounds__(1024) void k_scan1(const int* __restrict__ cnt,
                                                int* __restrict__ off, int* __restrict__ bsum) {
    __shared__ int sd[1024];
    int t = threadIdx.x;
    int i = blockIdx.x * 1024 + t;
    int v = (i < NODES) ? cnt[i] : 0;
    sd[t] = v; __syncthreads();
    for (int o = 1; o < 1024; o <<= 1) {
        int tv = (t >= o) ? sd[t - o] : 0;
        __syncthreads();
        sd[t] += tv; __syncthreads();
    }
    if (i < NODES) off[i] = sd[t] - v;           // exclusive within block
    if (t == 1023) bsum[blockIdx.x] = sd[1023];
}

__global__ void k_scan2(int* __restrict__ bsum, int* __restrict__ off) {
    if (threadIdx.x == 0 && blockIdx.x == 0) {
        int run = 0;
        for (int b = 0; b < NB; ++b) { int tv = bsum[b]; bsum[b] = run; run += tv; }
        off[NODES] = run;                        // == EP
    }
}

__global__ __launch_bounds__(1024) void k_scan3(int* __restrict__ off, const int* __restrict__ bsum,
                                                int* __restrict__ cursor) {
    int i = blockIdx.x * 1024 + threadIdx.x;
    if (i >= NODES) return;
    int o = off[i] + bsum[blockIdx.x];
    off[i] = o;
    cursor[i] = o;
}

__global__ __launch_bounds__(256) void k_scatter(const int* __restrict__ S, const int* __restrict__ D,
                                                 int* __restrict__ cursor, int* __restrict__ csr_src) {
    int e = blockIdx.x * blockDim.x + threadIdx.x;
    if (e >= EP) return;
    int s, d; edge_sd(e, S, D, s, d);
    int pos = atomicAdd(&cursor[d], 1);
    csr_src[pos] = s;
}

// ---------------- dense node kernels ----------------

// h0 = elu(x @ W_in + b_in). W staged in LDS; lane=node, wave-uniform channel group.
__global__ __launch_bounds__(256) void k_in_proj(const float* __restrict__ x,
                                                 const float* __restrict__ W,
                                                 const float* __restrict__ b,
                                                 float* __restrict__ h) {
    __shared__ float Wl[INCH * HIDD];   // 24 KB
    int tid = threadIdx.x;
    for (int i = tid; i < INCH * HIDD; i += 256) Wl[i] = W[i];
    __syncthreads();

    int node = blockIdx.x * 64 + (tid & 63);
    if (node >= NODES) return;
    int cbase = (tid >> 6) * CHD;       // 0,24,48,72 (wave-uniform)
    const float* __restrict__ xr = x + (size_t)node * INCH;

    float acc[CHD];
#pragma unroll
    for (int j = 0; j < CHD; ++j) acc[j] = b[cbase + j];

#pragma unroll
    for (int k0 = 0; k0 < INCH; k0 += 4) {
        float4 xv = *(const float4*)(xr + k0);
        const float xvv[4] = {xv.x, xv.y, xv.z, xv.w};
#pragma unroll
        for (int kk = 0; kk < 4; ++kk) {
#pragma unroll
            for (int j = 0; j < CHD; ++j)
                acc[j] = fmaf(xvv[kk], Wl[(k0 + kk) * HIDD + cbase + j], acc[j]);
        }
    }
    float* hrow = h + (size_t)node * HIDD + cbase;
#pragma unroll
    for (int j = 0; j < CHD; ++j) hrow[j] = elu1(acc[j]);
}

// hp = h @ Wg[i]; fused per-head attention dots (cgroup == head).
__global__ __launch_bounds__(256) void k_proj(const float* __restrict__ h,
                                              const float* __restrict__ W,
                                              const float* __restrict__ asrc,
                                              const float* __restrict__ adst,
                                              float* __restrict__ hp,
                                              float* __restrict__ as_,
                                              float* __restrict__ ad_) {
    int node = blockIdx.x * 64 + (threadIdx.x & 63);
    if (node >= NODES) return;
    int head = __builtin_amdgcn_readfirstlane(threadIdx.x >> 6);   // 0..3
    int cbase = head * CHD;
    const float* __restrict__ Wc = W + cbase;
    const float* __restrict__ hr = h + (size_t)node * HIDD;

    float acc[CHD] = {};
#pragma unroll
    for (int k0 = 0; k0 < HIDD; k0 += 4) {
        float4 hv = *(const float4*)(hr + k0);
        const float hvv[4] = {hv.x, hv.y, hv.z, hv.w};
#pragma unroll
        for (int kk = 0; kk < 4; ++kk) {
#pragma unroll
            for (int j = 0; j < CHD; ++j)
                acc[j] = fmaf(hvv[kk], Wc[(k0 + kk) * HIDD + j], acc[j]);
        }
    }
    float* orow = hp + (size_t)node * HIDD + cbase;
#pragma unroll
    for (int j = 0; j < CHD; ++j) orow[j] = acc[j];

    const float* __restrict__ s = asrc + head * CHD;
    const float* __restrict__ d = adst + head * CHD;
    float sa = 0.f, da = 0.f;
#pragma unroll
    for (int j = 0; j < CHD; ++j) { sa = fmaf(acc[j], s[j], sa); da = fmaf(acc[j], d[j], da); }
    as_[node * NHEAD + head] = sa;
    ad_[node * NHEAD + head] = da;
}

// ---------------- fused edge phase: online softmax + aggregate + BN + residual + pool ----------------

__global__ __launch_bounds__(256) void k_edge(const int* __restrict__ off,
                                              const int* __restrict__ csr,
                                              const float* __restrict__ as_,
                                              const float* __restrict__ ad_,
                                              const float* __restrict__ hp,
                                              const float* __restrict__ bg,
                                              const float* __restrict__ gamma,
                                              const float* __restrict__ beta,
                                              const float* __restrict__ rm,
                                              const float* __restrict__ rv,
                                              float* __restrict__ h,
                                              const int* __restrict__ batch,
                                              float* __restrict__ pooled) {
    int node = blockIdx.x * 4 + (threadIdx.x >> 6);
    if (node >= NODES) return;
    int lane = threadIdx.x & 63;
    int beg = off[node], end = off[node + 1];

    // ---- pass 1: online max+sum per head (lane -> head lane&3, slot lane>>2) ----
    int hd = lane & 3, slot = lane >> 2;
    float adv = ad_[node * NHEAD + hd];
    float m = NEGBIG, z = 0.f;
    for (int i = beg + slot; i < end; i += 16) {
        float ev = as_[csr[i] * NHEAD + hd] + adv;
        ev = ev > 0.f ? ev : 0.2f * ev;
        float mn = fmaxf(m, ev);
        z = z * __expf(m - mn) + __expf(ev - mn);
        m = mn;
    }
#pragma unroll
    for (int o = 4; o < 64; o <<= 1) {
        float mo = __shfl_xor(m, o), zo = __shfl_xor(z, o);
        float mn = fmaxf(m, mo);
        z = z * __expf(m - mn) + zo * __expf(mo - mn);
        m = mn;
    }
    // every lane now holds stats for head lane&3

    // ---- pass 2: aggregate; lane owns ch0=lane, ch1=64+lane(lane<32) ----
    const int ch0 = lane,      h0 = lane / CHD;
    const int ch1 = 64 + lane, h1 = (64 + lane) / CHD;
    float m0 = __shfl(m, h0), iz0 = 1.f / (__shfl(z, h0) + 1e-16f), av0 = __shfl(adv, h0);
    float m1 = __shfl(m, h1), iz1 = 1.f / (__shfl(z, h1) + 1e-16f), av1 = __shfl(adv, h1);

    float a0 = 0.f, a1 = 0.f;
    for (int i = beg; i < end; ++i) {
        int s = csr[i];
        const float* asr = as_ + (size_t)s * NHEAD;
        const float* hr  = hp  + (size_t)s * HIDD;
        float e0 = asr[h0] + av0; e0 = e0 > 0.f ? e0 : 0.2f * e0;
        a0 = fmaf(hr[ch0], __expf(e0 - m0) * iz0, a0);
        if (lane < 32) {
            float e1 = asr[h1] + av1; e1 = e1 > 0.f ? e1 : 0.2f * e1;
            a1 = fmaf(hr[ch1], __expf(e1 - m1) * iz1, a1);
        }
    }

    int gi = batch[node] * HIDD;
    {
        float hn = a0 + bg[ch0];
        hn = (hn - rm[ch0]) / sqrtf(rv[ch0] + BNEPS) * gamma[ch0] + beta[ch0];
        float hv = h[(size_t)node * HIDD + ch0] + elu1(hn);
        h[(size_t)node * HIDD + ch0] = hv;
        atomicAdd(&pooled[gi + ch0], hv);
    }
    if (lane < 32) {
        float hn = a1 + bg[ch1];
        hn = (hn - rm[ch1]) / sqrtf(rv[ch1] + BNEPS) * gamma[ch1] + beta[ch1];
        float hv = h[(size_t)node * HIDD + ch1] + elu1(hn);
        h[(size_t)node * HIDD + ch1] = hv;
        atomicAdd(&pooled[gi + ch1], hv);
    }
}

// ---------------- per-graph MLP head ----------------

__global__ __launch_bounds__(128) void k_head(const float* __restrict__ pooled,
                                              const float* __restrict__ Wjk, const float* __restrict__ bjk,
                                              const float* __restrict__ Wh1, const float* __restrict__ bh1,
                                              const float* __restrict__ Wh2, const float* __restrict__ bh2,
                                              float* __restrict__ out) {
    __shared__ float pin[NLAY * HIDD];
    __shared__ float z1[HIDD];
    __shared__ float z2[HIDD];
    int g = blockIdx.x, tid = threadIdx.x;
    for (int idx = tid; idx < NLAY * HIDD; idx += blockDim.x) {
        int l = idx / HIDD, c = idx % HIDD;
        pin[idx] = pooled[(size_t)l * NGRF * HIDD + (size_t)g * HIDD + c];
    }
    __syncthreads();
    for (int c = tid; c < HIDD; c += blockDim.x) {
        float a = bjk[c];
        for (int k = 0; k < NLAY * HIDD; ++k) a = fmaf(pin[k], Wjk[k * HIDD + c], a);
        z1[c] = elu1(a);
    }
    __syncthreads();
    for (int c = tid; c < HIDD; c += blockDim.x) {
        float a = bh1[c];
#pragma unroll
        for (int k = 0; k < HIDD; ++k) a = fmaf(z1[k], Wh1[k * HIDD + c], a);
        z2[c] = fmaxf(a, 0.f);
    }
    __syncthreads();
    if (tid < 64) {
        float a = 0.f;
        for (int k = tid; k < HIDD; k += 64) a = fmaf(z2[k], Wh2[k], a);
#pragma unroll
        for (int o = 32; o > 0; o >>= 1) a += __shfl_down(a, o);
        if (tid == 0) out[g] = a + bh2[0];
    }
}

extern "C" void kernel_launch(void* const* d_in, const int* in_sizes, int n_in,
                              void* d_out, int out_size, void* d_ws, size_t ws_size,
                              hipStream_t stream) {
    const float* x     = (const float*)d_in[0];
    const int*   ei    = (const int*)d_in[1];
    const int*   batch = (const int*)d_in[2];
    const float* W_in  = (const float*)d_in[3];
    const float* b_in  = (const float*)d_in[4];
    const float* Wg    = (const float*)d_in[5];
    const float* att_s = (const float*)d_in[6];
    const float* att_d = (const float*)d_in[7];
    const float* bg    = (const float*)d_in[8];
    const float* gamma = (const float*)d_in[9];
    const float* beta  = (const float*)d_in[10];
    const float* rm    = (const float*)d_in[11];
    const float* rv    = (const float*)d_in[12];
    const float* Wjk   = (const float*)d_in[13];
    const float* bjk   = (const float*)d_in[14];
    const float* Wh1   = (const float*)d_in[15];
    const float* bh1   = (const float*)d_in[16];
    const float* Wh2   = (const float*)d_in[17];
    const float* bh2   = (const float*)d_in[18];
    float* out = (float*)d_out;

    const int* S = ei;
    const int* Dd = ei + EDGES;

    // workspace layout
    float* ws = (float*)d_ws;
    float* h      = ws;                               // N*96
    float* hp     = h      + (size_t)NODES * HIDD;    // N*96
    float* as_    = hp     + (size_t)NODES * HIDD;    // N*4
    float* ad_    = as_    + (size_t)NODES * NHEAD;   // N*4
    float* pooled = ad_    + (size_t)NODES * NHEAD;   // L*G*96
    int*   off    = (int*)(pooled + (size_t)NLAY * NGRF * HIDD);  // N+1
    int*   cursor = off    + NODES + 1;               // N
    int*   csr    = cursor + NODES;                   // EP
    int*   cnt    = csr    + EP;                      // N
    int*   bsum   = cnt    + NODES;                   // NB

    hipMemsetAsync(pooled, 0, sizeof(float) * NLAY * NGRF * HIDD, stream);
    hipMemsetAsync(cnt, 0, sizeof(int) * NODES, stream);

    const int TB = 256;
    int gE    = (EP + TB - 1) / TB;
    int gTile = (NODES + 63) / 64;   // 782 blocks, 64 nodes each
    int gWave = NODES / 4;           // 12500

    // CSR build (graph is identical across layers)
    k_count<<<gE, TB, 0, stream>>>(S, Dd, cnt);
    k_scan1<<<NB, 1024, 0, stream>>>(cnt, off, bsum);
    k_scan2<<<1, 64, 0, stream>>>(bsum, off);
    k_scan3<<<NB, 1024, 0, stream>>>(off, bsum, cursor);
    k_scatter<<<gE, TB, 0, stream>>>(S, Dd, cursor, csr);

    k_in_proj<<<gTile, TB, 0, stream>>>(x, W_in, b_in, h);

    for (int i = 0; i < NLAY; ++i) {
        k_proj<<<gTile, TB, 0, stream>>>(h, Wg + (size_t)i * HIDD * HIDD,
                                         att_s + i * NHEAD * CHD, att_d + i * NHEAD * CHD,
                                         hp, as_, ad_);
        k_edge<<<gWave, TB, 0, stream>>>(off, csr, as_, ad_, hp,
                                         bg + i * HIDD, gamma + i * HIDD, beta + i * HIDD,
                                         rm + i * HIDD, rv + i * HIDD, h, batch,
                                         pooled + (size_t)i * NGRF * HIDD);
    }

    k_head<<<NGRF, 128, 0, stream>>>(pooled, Wjk, bjk, Wh1, bh1, Wh2, bh2, out);
}